// Round 1
// baseline (14231.320 us; speedup 1.0000x reference)
//
#include <hip/hip_runtime.h>

typedef __attribute__((ext_vector_type(8))) short bf16x8;
typedef __attribute__((ext_vector_type(4))) float f32x4;
typedef __attribute__((ext_vector_type(4))) unsigned int u32x4;

#define NWG_ 256

__device__ __forceinline__ unsigned short f2b(float x){
  union { float f; unsigned u; } v; v.f = x;
  unsigned r = v.u + 0x7FFFu + ((v.u >> 16) & 1u);
  return (unsigned short)(r >> 16);
}
__device__ __forceinline__ float b2f(unsigned short h){
  union { float f; unsigned u; } v; v.u = ((unsigned)h) << 16; return v.f;
}
__device__ __forceinline__ float rcpf_(float x){ return __builtin_amdgcn_rcpf(x); }
__device__ __forceinline__ float tanhf_(float x){
  x = fminf(15.f, fmaxf(-15.f, x));
  float e = __expf(2.f*x);
  return (e - 1.f) * rcpf_(e + 1.f);
}
__device__ __forceinline__ float sigf_(float x){
  x = fminf(30.f, fmaxf(-30.f, x));
  return rcpf_(1.f + __expf(-x));
}

// ---------------- conversion / layout prep ----------------
// hs_b   [4096][1024] bf16  = h_s
// Wcomb  [2560][1024] bf16  : rows 0..511  = w_a^T (n=h, k)
//                             rows 512..   = W_ih row (g*512+h) at r'=h*4+g (gate-interleaved)
// Wv     [512][512]   bf16  = v_a^T
// Whh_p  [2048][512]  bf16  = W_hh gate-interleaved (r'=h*4+g)
// bias_p [2048] f32         = (b_ih+b_hh) gate-interleaved
__global__ void k_convert(const float* __restrict__ h_s, const float* __restrict__ w_a,
                          const float* __restrict__ W_ih, const float* __restrict__ v_a,
                          const float* __restrict__ W_hh, const float* __restrict__ b_ih,
                          const float* __restrict__ b_hh,
                          unsigned short* __restrict__ hs_b, unsigned short* __restrict__ Wcomb,
                          unsigned short* __restrict__ Wv, unsigned short* __restrict__ Whh_p,
                          float* __restrict__ bias_p)
{
  const int total = 4194304 + 524288 + 2097152 + 262144 + 1048576 + 2048;
  for (int i = blockIdx.x*256 + threadIdx.x; i < total; i += gridDim.x*256) {
    int j = i;
    if (j < 4194304) { hs_b[j] = f2b(h_s[j]); continue; }
    j -= 4194304;
    if (j < 524288) { int k = j >> 9, n = j & 511;
      Wcomb[n*1024 + k] = f2b(w_a[k*512 + n]); continue; }
    j -= 524288;
    if (j < 2097152) { int rp = j >> 10, k = j & 1023;
      int h = rp >> 2, g = rp & 3;
      Wcomb[(512 + rp)*1024 + k] = f2b(W_ih[(g*512 + h)*1024 + k]); continue; }
    j -= 2097152;
    if (j < 262144) { int k = j >> 9, h = j & 511;
      Wv[h*512 + k] = f2b(v_a[k*512 + h]); continue; }
    j -= 262144;
    if (j < 1048576) { int rp = j >> 9, k = j & 511;
      int h = rp >> 2, g = rp & 3;
      Whh_p[rp*512 + k] = f2b(W_hh[(g*512 + h)*512 + k]); continue; }
    j -= 1048576;
    { int rp = j; int h = rp >> 2, g = rp & 3;
      bias_p[rp] = b_ih[g*512 + h] + b_hh[g*512 + h]; }
  }
}

// ---------------- generic bf16 MFMA GEMM ----------------
// C[m][n] = sum_k A[m][k]*B[k][n].  A bf16 [M][K] row-major.
// mode 0: B given fp32 [K][N] via two stacked row-sources (B0 rows<bsplit, B1 rest), converted in staging
// mode 1: B given bf16 [N][K] row-major (Bnk)
// Output split at n=ncut between C0/C1; cbf selects bf16 vs f32 C.
#define BM 128
#define BN 128
#define BK 64
#define LDT 72

__global__ __launch_bounds__(256) void k_gemm(
  const unsigned short* __restrict__ A,
  const float* __restrict__ B0, const float* __restrict__ B1, int bsplit,
  const unsigned short* __restrict__ Bnk, int mode,
  void* __restrict__ C0, void* __restrict__ C1, int ncut, int ldc0, int ldc1, int cbf,
  int M, int N, int K)
{
  __shared__ unsigned short As[BM*LDT];
  __shared__ unsigned short Bs[BN*LDT];
  const int tx = threadIdx.x;
  const int m0 = blockIdx.x * BM, n0 = blockIdx.y * BN;
  const int wave = tx >> 6, lane = tx & 63;
  const int wm = (wave >> 1) * 64, wn = (wave & 1) * 64;
  const int q = lane >> 4, r16 = lane & 15;
  f32x4 acc[4][4];
  #pragma unroll
  for (int i=0;i<4;i++)
    #pragma unroll
    for (int j=0;j<4;j++) acc[i][j] = (f32x4){0.f,0.f,0.f,0.f};

  for (int k0 = 0; k0 < K; k0 += BK) {
    #pragma unroll
    for (int i = 0; i < 4; ++i) {
      int idx = tx + i*256;
      int row = idx >> 3, piece = idx & 7;
      *(u32x4*)&As[row*LDT + piece*8] =
        *(const u32x4*)&A[(size_t)(m0+row)*K + k0 + piece*8];
    }
    if (mode == 0) {
      #pragma unroll
      for (int i = 0; i < 8; ++i) {
        int idx = tx + i*256;
        int kk = idx >> 5, nn = (idx & 31)*4;
        int kg = k0 + kk;
        const float* src = (kg < bsplit) ? (B0 + (size_t)kg*N) : (B1 + (size_t)(kg - bsplit)*N);
        f32x4 v = *(const f32x4*)&src[n0 + nn];
        Bs[(nn+0)*LDT + kk] = f2b(v.x);
        Bs[(nn+1)*LDT + kk] = f2b(v.y);
        Bs[(nn+2)*LDT + kk] = f2b(v.z);
        Bs[(nn+3)*LDT + kk] = f2b(v.w);
      }
    } else {
      #pragma unroll
      for (int i = 0; i < 4; ++i) {
        int idx = tx + i*256;
        int row = idx >> 3, piece = idx & 7;
        *(u32x4*)&Bs[row*LDT + piece*8] =
          *(const u32x4*)&Bnk[(size_t)(n0+row)*K + k0 + piece*8];
      }
    }
    __syncthreads();
    #pragma unroll
    for (int kk = 0; kk < BK; kk += 32) {
      bf16x8 af[4], bfv[4];
      #pragma unroll
      for (int i=0;i<4;i++) af[i] = *(const bf16x8*)&As[(wm + i*16 + r16)*LDT + kk + q*8];
      #pragma unroll
      for (int j=0;j<4;j++) bfv[j] = *(const bf16x8*)&Bs[(wn + j*16 + r16)*LDT + kk + q*8];
      #pragma unroll
      for (int i=0;i<4;i++)
        #pragma unroll
        for (int j=0;j<4;j++)
          acc[i][j] = __builtin_amdgcn_mfma_f32_16x16x32_bf16(af[i], bfv[j], acc[i][j], 0,0,0);
    }
    __syncthreads();
  }
  #pragma unroll
  for (int i=0;i<4;i++)
    #pragma unroll
    for (int j=0;j<4;j++) {
      int n = n0 + wn + j*16 + r16;
      #pragma unroll
      for (int reg=0; reg<4; ++reg) {
        int m = m0 + wm + i*16 + q*4 + reg;
        float v = acc[i][j][reg];
        if (n < ncut) {
          if (cbf) ((unsigned short*)C0)[(size_t)m*ldc0 + n] = f2b(v);
          else     ((float*)C0)[(size_t)m*ldc0 + n] = v;
        } else {
          if (cbf) ((unsigned short*)C1)[(size_t)m*ldc1 + (n-ncut)] = f2b(v);
          else     ((float*)C1)[(size_t)m*ldc1 + (n-ncut)] = v;
        }
      }
    }
}

// ---------------- persistent recurrence kernel ----------------
struct BarT { unsigned cnt; unsigned gen; };

__device__ void gbar(BarT* b, int* dead) {
  __syncthreads();
  if (*dead) return;
  if (threadIdx.x == 0) {
    unsigned g = __hip_atomic_load(&b->gen, __ATOMIC_RELAXED, __HIP_MEMORY_SCOPE_AGENT);
    unsigned t = __hip_atomic_fetch_add(&b->cnt, 1u, __ATOMIC_ACQ_REL, __HIP_MEMORY_SCOPE_AGENT);
    if (t == (unsigned)(NWG_ - 1)) {
      __hip_atomic_store(&b->cnt, 0u, __ATOMIC_RELAXED, __HIP_MEMORY_SCOPE_AGENT);
      __hip_atomic_fetch_add(&b->gen, 1u, __ATOMIC_RELEASE, __HIP_MEMORY_SCOPE_AGENT);
    } else {
      long sp = 0;
      while (__hip_atomic_load(&b->gen, __ATOMIC_ACQUIRE, __HIP_MEMORY_SCOPE_AGENT) == g) {
        __builtin_amdgcn_s_sleep(4);
        if (++sp > 2000000L) { *dead = 1; break; }  // liveness bail-out
      }
    }
  }
  __syncthreads();
}

// Abf [2048][1536] bf16: row t*32+b = [ s_{t+1} (512) | ct_t (1024) ]  -> A of vocab GEMM
__global__ __launch_bounds__(256) void k_recur(
  const unsigned short* __restrict__ wa_h,   // [4096][512] bf16
  const unsigned short* __restrict__ G,      // [4096][2048] bf16 (h_s @ W_ih^T, gate-interleaved)
  const unsigned short* __restrict__ hs_b,   // [4096][1024] bf16
  const unsigned short* __restrict__ Wv,     // [512][512]  bf16 (v_a^T)
  const unsigned short* __restrict__ Whh_p,  // [2048][512] bf16
  const float* __restrict__ bias_p,          // [2048]
  const float* __restrict__ s_mask,          // [128*32]
  const float* __restrict__ u_a,             // [512]
  float* __restrict__ c_st,                  // [32][512]
  float* __restrict__ sva_g,                 // [32][512]
  float* __restrict__ whh_g,                 // [32][2048]
  float* __restrict__ alpha_g,               // [32][128]
  unsigned short* __restrict__ Abf,
  BarT* bar)
{
  __shared__ float LDS[2304];
  __shared__ int s_dead;
  const int w = blockIdx.x, tx = threadIdx.x;
  if (tx == 0) s_dead = 0;
  { int gid = w*256 + tx; if (gid < 32*512) c_st[gid] = 0.f; }
  gbar(bar, &s_dead);

  for (int t = 0; t < 64; ++t) {
    // ---- P1: sva = s@v_a  and  whh = s@W_hh^T  (MFMA, N=2560 cols over 160 WGs) ----
    if (w < 160) {
      if (t == 0) {
        for (int o = tx; o < 512; o += 256) {
          int b = o >> 4, rl = o & 15;
          int nc = w*16 + rl;
          if (nc < 512) sva_g[b*512 + nc] = 0.f;
          else          whh_g[b*2048 + (nc - 512)] = 0.f;
        }
      } else {
        const int wv = tx >> 6, lane = tx & 63;
        const int q = lane >> 4, rl = lane & 15;
        const int ncol = w*16 + rl;
        const unsigned short* bp = (ncol < 512) ? (Wv + (size_t)ncol*512)
                                                : (Whh_p + (size_t)(ncol-512)*512);
        f32x4 a0 = (f32x4){0.f,0.f,0.f,0.f}, a1 = (f32x4){0.f,0.f,0.f,0.f};
        const size_t arow0 = ((size_t)(t-1)*32 + rl) * 1536;
        const size_t arow1 = ((size_t)(t-1)*32 + 16 + rl) * 1536;
        #pragma unroll
        for (int ks = 0; ks < 4; ++ks) {
          int kg = (wv*4 + ks)*32 + q*8;
          bf16x8 fa0 = *(const bf16x8*)&Abf[arow0 + kg];
          bf16x8 fa1 = *(const bf16x8*)&Abf[arow1 + kg];
          bf16x8 fb  = *(const bf16x8*)&bp[kg];
          a0 = __builtin_amdgcn_mfma_f32_16x16x32_bf16(fa0, fb, a0, 0,0,0);
          a1 = __builtin_amdgcn_mfma_f32_16x16x32_bf16(fa1, fb, a1, 0,0,0);
        }
        #pragma unroll
        for (int reg = 0; reg < 4; ++reg) {
          LDS[(wv*32 + (q*4 + reg))*16 + rl]      = a0[reg];
          LDS[(wv*32 + (16 + q*4 + reg))*16 + rl] = a1[reg];
        }
        __syncthreads();
        for (int o = tx; o < 512; o += 256) {
          int b = o >> 4, rlo = o & 15;
          float v = LDS[(b)*16 + rlo] + LDS[(32 + b)*16 + rlo]
                  + LDS[(64 + b)*16 + rlo] + LDS[(96 + b)*16 + rlo];
          int nc = w*16 + rlo;
          if (nc < 512) sva_g[b*512 + nc] = v;
          else          whh_g[b*2048 + (nc - 512)] = v;
        }
      }
    }
    gbar(bar, &s_dead);

    // ---- P2: scores/softmax/alpha per b (32 WGs) ----
    if (w < 32) {
      const int b = w;
      float* sva_l = LDS;
      float* ua_l  = LDS + 512;
      float* red   = LDS + 1024;
      float* sc    = LDS + 1280;
      sva_l[tx] = sva_g[b*512 + tx]; sva_l[tx+256] = sva_g[b*512 + tx + 256];
      ua_l[tx] = u_a[tx]; ua_l[tx+256] = u_a[tx+256];
      __syncthreads();
      {
        const int si = tx >> 1, half = tx & 1;
        const unsigned short* wr = wa_h + ((size_t)si*32 + b)*512 + half*256;
        const float* sv = sva_l + half*256;
        const float* ua = ua_l + half*256;
        float acc = 0.f;
        #pragma unroll 4
        for (int k = 0; k < 256; ++k) {
          float x = b2f(wr[k]) + sv[k];
          acc += tanhf_(x) * ua[k];
        }
        red[tx] = acc;
      }
      __syncthreads();
      if (tx < 128) sc[tx] = (red[2*tx] + red[2*tx+1]) * s_mask[tx*32 + b];
      __syncthreads();
      if (tx < 64) red[tx] = fmaxf(sc[tx], sc[tx+64]);
      __syncthreads();
      if (tx < 32) red[tx] = fmaxf(red[tx], red[tx+32]);
      __syncthreads();
      if (tx < 16) red[tx] = fmaxf(red[tx], red[tx+16]);
      __syncthreads();
      if (tx < 8) red[tx] = fmaxf(red[tx], red[tx+8]);
      __syncthreads();
      if (tx < 4) red[tx] = fmaxf(red[tx], red[tx+4]);
      __syncthreads();
      if (tx < 2) red[tx] = fmaxf(red[tx], red[tx+2]);
      __syncthreads();
      if (tx == 0) red[0] = fmaxf(red[0], red[1]);
      __syncthreads();
      float mx = red[0];
      __syncthreads();
      if (tx < 128) sc[tx] = __expf(sc[tx] - mx);
      __syncthreads();
      if (tx < 64) red[tx] = sc[tx] + sc[tx+64];
      __syncthreads();
      if (tx < 32) red[tx] += red[tx+32];
      __syncthreads();
      if (tx < 16) red[tx] += red[tx+16];
      __syncthreads();
      if (tx < 8) red[tx] += red[tx+8];
      __syncthreads();
      if (tx < 4) red[tx] += red[tx+4];
      __syncthreads();
      if (tx < 2) red[tx] += red[tx+2];
      __syncthreads();
      if (tx == 0) red[0] += red[1];
      __syncthreads();
      float inv = rcpf_(red[0]);
      if (tx < 128) alpha_g[b*128 + tx] = sc[tx] * inv;
    }
    gbar(bar, &s_dead);

    // ---- P3: gates = sum_s alpha*G + whh + bias, LSTM; and ct = sum_s alpha*h_s ----
    {
      const int b = w >> 3, ch = w & 7;
      float* al = LDS;
      float* gl = LDS + 128;
      if (tx < 128) al[tx] = alpha_g[b*128 + tx];
      __syncthreads();
      const int n = ch*256 + tx;     // r' index
      const unsigned short* gp = G + (size_t)b*2048 + n;
      float acc = 0.f;
      #pragma unroll 4
      for (int s = 0; s < 128; ++s) { acc += al[s] * b2f(*gp); gp += 65536; }
      acc += whh_g[b*2048 + n] + bias_p[n];
      gl[tx] = acc;
      __syncthreads();
      if (tx < 64) {
        int h = ch*64 + tx;
        float iv = gl[tx*4+0], fv = gl[tx*4+1], gv = gl[tx*4+2], ov = gl[tx*4+3];
        float co = c_st[b*512 + h];
        float cn = sigf_(fv)*co + sigf_(iv)*tanhf_(gv);
        float sn = sigf_(ov)*tanhf_(cn);
        c_st[b*512 + h] = cn;
        Abf[((size_t)t*32 + b)*1536 + h] = f2b(sn);
      }
      __syncthreads();
      if (w < 128) {
        const int b2 = w >> 2, jc = w & 3;
        if (tx < 128) al[tx] = alpha_g[b2*128 + tx];
        __syncthreads();
        const int jj = jc*256 + tx;
        const unsigned short* hp = hs_b + (size_t)b2*1024 + jj;
        float acc2 = 0.f;
        #pragma unroll 4
        for (int s = 0; s < 128; ++s) { acc2 += al[s] * b2f(*hp); hp += 32768; }
        Abf[((size_t)t*32 + b2)*1536 + 512 + jj] = f2b(acc2);
      }
    }
    gbar(bar, &s_dead);
  }
}

// ---------------- softmax / loss over logits (in d_out, in-place) ----------------
__global__ __launch_bounds__(256) void k_rowsum(const float* __restrict__ L, float* __restrict__ Z)
{
  __shared__ float r4[4];
  const int row = blockIdx.x, tx = threadIdx.x;
  const float* p = L + (size_t)row*32000;
  float s = 0.f;
  for (int n = tx; n < 32000; n += 256) s += __expf(p[n]);
  for (int o = 32; o > 0; o >>= 1) s += __shfl_down(s, o, 64);
  if ((tx & 63) == 0) r4[tx >> 6] = s;
  __syncthreads();
  if (tx == 0) Z[row] = r4[0] + r4[1] + r4[2] + r4[3];
}

__global__ __launch_bounds__(64) void k_loss(const float* __restrict__ L, const float* __restrict__ Z,
                                             const int* __restrict__ t_idx, const float* __restrict__ t_mask,
                                             float* __restrict__ out)
{
  const int b = blockIdx.x, t = threadIdx.x;
  const int row = t*32 + b;
  int id = t_idx[t*32 + b];
  float m = t_mask[t*32 + b];
  float l = L[(size_t)row*32000 + id];
  float v = (__logf(Z[row]) - l) * m;
  float vm = v, mm = m;
  for (int o = 32; o > 0; o >>= 1) { vm += __shfl_down(vm, o, 64); mm += __shfl_down(mm, o, 64); }
  if (t == 0) out[b] = vm / mm;
}

__global__ __launch_bounds__(256) void k_s2(float* __restrict__ L, const float* __restrict__ Z)
{
  const int row = blockIdx.x, tx = threadIdx.x;
  float* p = L + (size_t)row*32000;
  float rz = 1.f / Z[row];
  for (int n = tx; n < 32000; n += 256) p[n] = __expf(p[n]) * rz;
}

// ---------------- host ----------------
extern "C" void kernel_launch(void* const* d_in, const int* in_sizes, int n_in,
                              void* d_out, int out_size, void* d_ws, size_t ws_size,
                              hipStream_t stream)
{
  (void)in_sizes; (void)n_in; (void)out_size; (void)ws_size;
  const float* h_s    = (const float*)d_in[0];
  const float* s_mask = (const float*)d_in[1];
  const float* w_a    = (const float*)d_in[2];
  const float* v_a    = (const float*)d_in[3];
  const float* u_a    = (const float*)d_in[4];
  const float* w_b    = (const float*)d_in[5];
  const float* v_b    = (const float*)d_in[6];
  const float* W_ih   = (const float*)d_in[7];
  const float* W_hh   = (const float*)d_in[8];
  const float* b_ih   = (const float*)d_in[9];
  const float* b_hh   = (const float*)d_in[10];
  const float* t_mask = (const float*)d_in[11];
  const int*   t_idx  = (const int*)d_in[12];
  float* out = (float*)d_out;
  float* logits = out + 32;   // p_gen region [2048][32000]

  char* w = (char*)d_ws;
  size_t off = 0;
  auto take = [&](size_t bytes) -> void* {
    void* p = w + off; off += (bytes + 255) & ~(size_t)255; return p;
  };
  BarT* bar              = (BarT*)take(256);
  float* c_st            = (float*)take((size_t)32*512*4);
  float* sva_g           = (float*)take((size_t)32*512*4);
  float* whh_g           = (float*)take((size_t)32*2048*4);
  float* alpha_g         = (float*)take((size_t)32*128*4);
  float* Z               = (float*)take((size_t)2048*4);
  float* bias_p          = (float*)take((size_t)2048*4);
  unsigned short* hs_b   = (unsigned short*)take((size_t)4096*1024*2);
  unsigned short* Wcomb  = (unsigned short*)take((size_t)2560*1024*2);
  unsigned short* Wv     = (unsigned short*)take((size_t)512*512*2);
  unsigned short* Whh_p  = (unsigned short*)take((size_t)2048*512*2);
  unsigned short* wa_hb  = (unsigned short*)take((size_t)4096*512*2);
  unsigned short* G      = (unsigned short*)take((size_t)4096*2048*2);
  unsigned short* Abf    = (unsigned short*)take((size_t)2048*1536*2);

  hipMemsetAsync(bar, 0, 256, stream);
  k_convert<<<4096, 256, 0, stream>>>(h_s, w_a, W_ih, v_a, W_hh, b_ih, b_hh,
                                      hs_b, Wcomb, Wv, Whh_p, bias_p);
  // [wa_h | G] = h_s @ [w_a | W_ih^T(perm)] : M=4096, N=2560, K=1024
  k_gemm<<<dim3(32,20), 256, 0, stream>>>(hs_b, nullptr, nullptr, 0, Wcomb, 1,
                                          wa_hb, G, 512, 512, 2048, 1,
                                          4096, 2560, 1024);
  k_recur<<<NWG_, 256, 0, stream>>>(wa_hb, G, hs_b, Wv, Whh_p, bias_p, s_mask, u_a,
                                    c_st, sva_g, whh_g, alpha_g, Abf, bar);
  // logits = [s_new|ct] @ [w_b; v_b] : M=2048, N=32000, K=1536
  k_gemm<<<dim3(16,250), 256, 0, stream>>>(Abf, w_b, v_b, 512, nullptr, 0,
                                           logits, logits, 32000, 32000, 32000, 0,
                                           2048, 32000, 1536);
  k_rowsum<<<2048, 256, 0, stream>>>(logits, Z);
  k_loss<<<32, 64, 0, stream>>>(logits, Z, t_idx, t_mask, out);
  k_s2<<<2048, 256, 0, stream>>>(logits, Z);
}

// Round 2
// 3007.550 us; speedup vs baseline: 4.7319x; 4.7319x over previous
//
#include <hip/hip_runtime.h>

typedef __attribute__((ext_vector_type(8))) short bf16x8;
typedef __attribute__((ext_vector_type(4))) float f32x4;
typedef __attribute__((ext_vector_type(4))) unsigned int u32x4;

#define NWG_ 256

__device__ __forceinline__ unsigned short f2b(float x){
  union { float f; unsigned u; } v; v.f = x;
  unsigned r = v.u + 0x7FFFu + ((v.u >> 16) & 1u);
  return (unsigned short)(r >> 16);
}
__device__ __forceinline__ float b2f(unsigned short h){
  union { float f; unsigned u; } v; v.u = ((unsigned)h) << 16; return v.f;
}
__device__ __forceinline__ float rcpf_(float x){ return __builtin_amdgcn_rcpf(x); }
__device__ __forceinline__ float tanhf_(float x){
  x = fminf(15.f, fmaxf(-15.f, x));
  float e = __expf(2.f*x);
  return (e - 1.f) * rcpf_(e + 1.f);
}
__device__ __forceinline__ float sigf_(float x){
  x = fminf(30.f, fmaxf(-30.f, x));
  return rcpf_(1.f + __expf(-x));
}

// ---------------- conversion / layout prep ----------------
__global__ void k_convert(const float* __restrict__ h_s, const float* __restrict__ w_a,
                          const float* __restrict__ W_ih, const float* __restrict__ v_a,
                          const float* __restrict__ W_hh, const float* __restrict__ b_ih,
                          const float* __restrict__ b_hh,
                          unsigned short* __restrict__ hs_b, unsigned short* __restrict__ Wcomb,
                          unsigned short* __restrict__ Wv, unsigned short* __restrict__ Whh_p,
                          float* __restrict__ bias_p)
{
  const int total = 4194304 + 524288 + 2097152 + 262144 + 1048576 + 2048;
  for (int i = blockIdx.x*256 + threadIdx.x; i < total; i += gridDim.x*256) {
    int j = i;
    if (j < 4194304) { hs_b[j] = f2b(h_s[j]); continue; }
    j -= 4194304;
    if (j < 524288) { int k = j >> 9, n = j & 511;
      Wcomb[n*1024 + k] = f2b(w_a[k*512 + n]); continue; }
    j -= 524288;
    if (j < 2097152) { int rp = j >> 10, k = j & 1023;
      int h = rp >> 2, g = rp & 3;
      Wcomb[(512 + rp)*1024 + k] = f2b(W_ih[(g*512 + h)*1024 + k]); continue; }
    j -= 2097152;
    if (j < 262144) { int k = j >> 9, h = j & 511;
      Wv[h*512 + k] = f2b(v_a[k*512 + h]); continue; }
    j -= 262144;
    if (j < 1048576) { int rp = j >> 9, k = j & 511;
      int h = rp >> 2, g = rp & 3;
      Whh_p[rp*512 + k] = f2b(W_hh[(g*512 + h)*512 + k]); continue; }
    j -= 1048576;
    { int rp = j; int h = rp >> 2, g = rp & 3;
      bias_p[rp] = b_ih[g*512 + h] + b_hh[g*512 + h]; }
  }
}

// transpose [1536][32000] fp32 (w_b stacked on v_b) -> Bt [32000][1536] bf16
__global__ __launch_bounds__(256) void k_convB(const float* __restrict__ w_b,
                                               const float* __restrict__ v_b,
                                               unsigned short* __restrict__ Bt)
{
  __shared__ unsigned short T[64*80];
  const int k0 = blockIdx.x*64, n0 = blockIdx.y*64;
  const int tx = threadIdx.x;
  const int kk = tx >> 4, nn = (tx & 15)*4;
  #pragma unroll
  for (int i = 0; i < 4; ++i) {
    int kr = k0 + kk + i*16;
    const float* src = (kr < 512) ? &w_b[(size_t)kr*32000 + n0 + nn]
                                  : &v_b[(size_t)(kr-512)*32000 + n0 + nn];
    f32x4 v = *(const f32x4*)src;
    T[(nn+0)*80 + kk + i*16] = f2b(v.x);
    T[(nn+1)*80 + kk + i*16] = f2b(v.y);
    T[(nn+2)*80 + kk + i*16] = f2b(v.z);
    T[(nn+3)*80 + kk + i*16] = f2b(v.w);
  }
  __syncthreads();
  #pragma unroll
  for (int i = 0; i < 2; ++i) {
    int p = tx + i*256;
    int nrow = p >> 3, kp = p & 7;
    *(u32x4*)&Bt[(size_t)(n0+nrow)*1536 + k0 + kp*8] = *(const u32x4*)&T[nrow*80 + kp*8];
  }
}

// ---------------- generic bf16 MFMA GEMM ----------------
#define BM 128
#define BN 128
#define BK 64
#define LDT 72

__global__ __launch_bounds__(256) void k_gemm(
  const unsigned short* __restrict__ A,
  const float* __restrict__ B0, const float* __restrict__ B1, int bsplit,
  const unsigned short* __restrict__ Bnk, int mode,
  void* __restrict__ C0, void* __restrict__ C1, int ncut, int ldc0, int ldc1, int cbf,
  float* __restrict__ Zp,
  int M, int N, int K)
{
  __shared__ unsigned short As[BM*LDT];
  __shared__ unsigned short Bs[BN*LDT];
  const int tx = threadIdx.x;
  const int m0 = blockIdx.x * BM, n0 = blockIdx.y * BN;
  const int wave = tx >> 6, lane = tx & 63;
  const int wm = (wave >> 1) * 64, wn = (wave & 1) * 64;
  const int q = lane >> 4, r16 = lane & 15;
  f32x4 acc[4][4];
  #pragma unroll
  for (int i=0;i<4;i++)
    #pragma unroll
    for (int j=0;j<4;j++) acc[i][j] = (f32x4){0.f,0.f,0.f,0.f};

  for (int k0 = 0; k0 < K; k0 += BK) {
    #pragma unroll
    for (int i = 0; i < 4; ++i) {
      int idx = tx + i*256;
      int row = idx >> 3, piece = idx & 7;
      *(u32x4*)&As[row*LDT + piece*8] =
        *(const u32x4*)&A[(size_t)(m0+row)*K + k0 + piece*8];
    }
    if (mode == 0) {
      #pragma unroll
      for (int i = 0; i < 8; ++i) {
        int idx = tx + i*256;
        int kk = idx >> 5, nn = (idx & 31)*4;
        int kg = k0 + kk;
        const float* src = (kg < bsplit) ? (B0 + (size_t)kg*N) : (B1 + (size_t)(kg - bsplit)*N);
        f32x4 v = *(const f32x4*)&src[n0 + nn];
        Bs[(nn+0)*LDT + kk] = f2b(v.x);
        Bs[(nn+1)*LDT + kk] = f2b(v.y);
        Bs[(nn+2)*LDT + kk] = f2b(v.z);
        Bs[(nn+3)*LDT + kk] = f2b(v.w);
      }
    } else {
      #pragma unroll
      for (int i = 0; i < 4; ++i) {
        int idx = tx + i*256;
        int row = idx >> 3, piece = idx & 7;
        *(u32x4*)&Bs[row*LDT + piece*8] =
          *(const u32x4*)&Bnk[(size_t)(n0+row)*K + k0 + piece*8];
      }
    }
    __syncthreads();
    #pragma unroll
    for (int kk = 0; kk < BK; kk += 32) {
      bf16x8 af[4], bfv[4];
      #pragma unroll
      for (int i=0;i<4;i++) af[i] = *(const bf16x8*)&As[(wm + i*16 + r16)*LDT + kk + q*8];
      #pragma unroll
      for (int j=0;j<4;j++) bfv[j] = *(const bf16x8*)&Bs[(wn + j*16 + r16)*LDT + kk + q*8];
      #pragma unroll
      for (int i=0;i<4;i++)
        #pragma unroll
        for (int j=0;j<4;j++)
          acc[i][j] = __builtin_amdgcn_mfma_f32_16x16x32_bf16(af[i], bfv[j], acc[i][j], 0,0,0);
    }
    __syncthreads();
  }
  // fused row-sum of exp(logits) for softmax denominator
  if (Zp) {
    #pragma unroll
    for (int i=0;i<4;i++)
      #pragma unroll
      for (int reg=0; reg<4; ++reg) {
        float z = __expf(acc[i][0][reg]) + __expf(acc[i][1][reg])
                + __expf(acc[i][2][reg]) + __expf(acc[i][3][reg]);
        z += __shfl_xor(z, 1, 64); z += __shfl_xor(z, 2, 64);
        z += __shfl_xor(z, 4, 64); z += __shfl_xor(z, 8, 64);
        if (r16 == 0) atomicAdd(&Zp[m0 + wm + i*16 + q*4 + reg], z);
      }
  }
  #pragma unroll
  for (int i=0;i<4;i++)
    #pragma unroll
    for (int j=0;j<4;j++) {
      int n = n0 + wn + j*16 + r16;
      #pragma unroll
      for (int reg=0; reg<4; ++reg) {
        int m = m0 + wm + i*16 + q*4 + reg;
        float v = acc[i][j][reg];
        if (n < ncut) {
          if (cbf) ((unsigned short*)C0)[(size_t)m*ldc0 + n] = f2b(v);
          else     ((float*)C0)[(size_t)m*ldc0 + n] = v;
        } else {
          if (cbf) ((unsigned short*)C1)[(size_t)m*ldc1 + (n-ncut)] = f2b(v);
          else     ((float*)C1)[(size_t)m*ldc1 + (n-ncut)] = v;
        }
      }
    }
}

// ---------------- grid barrier: split arrival + relaxed spin ----------------
// bar layout (unsigned): slot i at [i*32] (128B apart), master at [256], gen at [288]
__device__ __forceinline__ void gbar(unsigned* bar, int w, int* dead) {
  __syncthreads();
  if (*dead) return;
  if (threadIdx.x == 0) {
    unsigned* gen = bar + 288;
    unsigned g = __hip_atomic_load(gen, __ATOMIC_RELAXED, __HIP_MEMORY_SCOPE_AGENT);
    unsigned a = __hip_atomic_fetch_add(&bar[(w & 7)*32], 1u, __ATOMIC_ACQ_REL, __HIP_MEMORY_SCOPE_AGENT);
    bool flipped = false;
    if (a == 31u) {
      unsigned b = __hip_atomic_fetch_add(bar + 256, 1u, __ATOMIC_ACQ_REL, __HIP_MEMORY_SCOPE_AGENT);
      if (b == 7u) {
        #pragma unroll
        for (int i = 0; i < 8; ++i)
          __hip_atomic_store(&bar[i*32], 0u, __ATOMIC_RELAXED, __HIP_MEMORY_SCOPE_AGENT);
        __hip_atomic_store(bar + 256, 0u, __ATOMIC_RELAXED, __HIP_MEMORY_SCOPE_AGENT);
        __hip_atomic_store(gen, g + 1u, __ATOMIC_RELEASE, __HIP_MEMORY_SCOPE_AGENT);
        flipped = true;
      }
    }
    if (!flipped) {
      long sp = 0;
      while (__hip_atomic_load(gen, __ATOMIC_RELAXED, __HIP_MEMORY_SCOPE_AGENT) == g) {
        __builtin_amdgcn_s_sleep(8);
        if (++sp > 400000L) { *dead = 1; break; }
      }
    }
    __builtin_amdgcn_fence(__ATOMIC_ACQUIRE, "agent");
  }
  __syncthreads();
}

// ---------------- persistent recurrence kernel ----------------
// Abf [2048][1536] bf16: row t*32+b = [ s_{t+1} (512) | ct_t (1024) ]
__global__ __launch_bounds__(256) void k_recur(
  const unsigned short* __restrict__ wa_h,   // [4096][512] bf16
  const unsigned short* __restrict__ G,      // [4096][2048] bf16
  const unsigned short* __restrict__ hs_b,   // [4096][1024] bf16
  const unsigned short* __restrict__ Wv,     // [512][512]  bf16 (v_a^T)
  const unsigned short* __restrict__ Whh_p,  // [2048][512] bf16
  const float* __restrict__ bias_p,          // [2048]
  const float* __restrict__ s_mask,          // [128*32]
  const float* __restrict__ u_a,             // [512]
  float* __restrict__ c_st,                  // [32][512]
  float* __restrict__ sva_g,                 // [32][512]
  float* __restrict__ whh_g,                 // [32][2048]
  float* __restrict__ scores_g,              // [32][128]
  unsigned short* __restrict__ Abf,
  unsigned* bar)
{
  __shared__ float AL[128];
  __shared__ float GL[256];
  __shared__ float RD[2048];
  __shared__ int s_dead;
  const int w = blockIdx.x, tx = threadIdx.x;
  if (tx == 0) s_dead = 0;
  { int gid = w*256 + tx; if (gid < 32*512) c_st[gid] = 0.f; }
  gbar(bar, w, &s_dead);

  const int wave = tx >> 6, lane = tx & 63;
  const f32x4 ua0 = *(const f32x4*)&u_a[lane*8];
  const f32x4 ua1 = *(const f32x4*)&u_a[lane*8 + 4];

  for (int t = 0; t < 64; ++t) {
    // ---- P1: sva = s@v_a, whh = s@W_hh^T (batched MFMA over 160 WGs) ----
    if (w < 160) {
      if (t == 0) {
        for (int o = tx; o < 512; o += 256) {
          int b = o >> 4, rl = o & 15;
          int nc = w*16 + rl;
          if (nc < 512) sva_g[b*512 + nc] = 0.f;
          else          whh_g[b*2048 + (nc - 512)] = 0.f;
        }
      } else {
        const int q = lane >> 4, rl = lane & 15;
        const int ncol = w*16 + rl;
        const unsigned short* bp = (ncol < 512) ? (Wv + (size_t)ncol*512)
                                                : (Whh_p + (size_t)(ncol-512)*512);
        f32x4 a0 = (f32x4){0.f,0.f,0.f,0.f}, a1 = (f32x4){0.f,0.f,0.f,0.f};
        const size_t arow0 = ((size_t)(t-1)*32 + rl) * 1536;
        const size_t arow1 = ((size_t)(t-1)*32 + 16 + rl) * 1536;
        #pragma unroll
        for (int ks = 0; ks < 4; ++ks) {
          int kg = (wave*4 + ks)*32 + q*8;
          bf16x8 fa0 = *(const bf16x8*)&Abf[arow0 + kg];
          bf16x8 fa1 = *(const bf16x8*)&Abf[arow1 + kg];
          bf16x8 fb  = *(const bf16x8*)&bp[kg];
          a0 = __builtin_amdgcn_mfma_f32_16x16x32_bf16(fa0, fb, a0, 0,0,0);
          a1 = __builtin_amdgcn_mfma_f32_16x16x32_bf16(fa1, fb, a1, 0,0,0);
        }
        #pragma unroll
        for (int reg = 0; reg < 4; ++reg) {
          RD[(wave*32 + (q*4 + reg))*16 + rl]      = a0[reg];
          RD[(wave*32 + (16 + q*4 + reg))*16 + rl] = a1[reg];
        }
        __syncthreads();
        for (int o = tx; o < 512; o += 256) {
          int b = o >> 4, rlo = o & 15;
          float v = RD[(b)*16 + rlo] + RD[(32 + b)*16 + rlo]
                  + RD[(64 + b)*16 + rlo] + RD[(96 + b)*16 + rlo];
          int nc = w*16 + rlo;
          if (nc < 512) sva_g[b*512 + nc] = v;
          else          whh_g[b*2048 + (nc - 512)] = v;
        }
      }
    }
    gbar(bar, w, &s_dead);

    // ---- P2a: scores[s][b] spread over all 256 WGs (16 wa_h rows each) ----
    {
      #pragma unroll
      for (int r = 0; r < 4; ++r) {
        int p = w*16 + wave*4 + r;      // row of wa_h = s*32 + b
        int b = p & 31, s = p >> 5;
        bf16x8 wv8 = *(const bf16x8*)&wa_h[(size_t)p*512 + lane*8];
        const float* sv = &sva_g[b*512 + lane*8];
        f32x4 s0 = *(const f32x4*)sv, s1 = *(const f32x4*)(sv + 4);
        float acc;
        acc  = tanhf_(b2f(wv8[0]) + s0.x) * ua0.x;
        acc += tanhf_(b2f(wv8[1]) + s0.y) * ua0.y;
        acc += tanhf_(b2f(wv8[2]) + s0.z) * ua0.z;
        acc += tanhf_(b2f(wv8[3]) + s0.w) * ua0.w;
        acc += tanhf_(b2f(wv8[4]) + s1.x) * ua1.x;
        acc += tanhf_(b2f(wv8[5]) + s1.y) * ua1.y;
        acc += tanhf_(b2f(wv8[6]) + s1.z) * ua1.z;
        acc += tanhf_(b2f(wv8[7]) + s1.w) * ua1.w;
        #pragma unroll
        for (int o = 32; o > 0; o >>= 1) acc += __shfl_down(acc, o, 64);
        if (lane == 0) scores_g[b*128 + s] = acc * s_mask[s*32 + b];
      }
    }
    gbar(bar, w, &s_dead);

    // ---- P3: per-WG (b, chunk): softmax (redundant), gates+LSTM, ct ----
    {
      const int b = w >> 3, ch = w & 7;
      if (tx < 128) AL[tx] = __expf(scores_g[b*128 + tx]);
      __syncthreads();
      if (tx < 64) {
        float sm = AL[tx] + AL[tx + 64];
        #pragma unroll
        for (int o = 32; o > 0; o >>= 1) sm += __shfl_down(sm, o, 64);
        if (tx == 0) GL[0] = rcpf_(sm);
      }
      __syncthreads();
      float inv = GL[0];
      __syncthreads();
      if (tx < 128) AL[tx] *= inv;
      __syncthreads();
      // gates partial: sum_s alpha[s] * G[s*32+b][n], n = ch*256 + cg*8 .. +8
      {
        const int cg = tx & 31, sg = tx >> 5;   // 8 s-groups of 16
        const int nn = ch*256 + cg*8;
        float a8[8] = {0.f,0.f,0.f,0.f,0.f,0.f,0.f,0.f};
        #pragma unroll
        for (int k = 0; k < 16; ++k) {
          int s = sg*16 + k;
          float av = AL[s];
          bf16x8 g8 = *(const bf16x8*)&G[((size_t)s*32 + b)*2048 + nn];
          a8[0] += av * b2f(g8[0]); a8[1] += av * b2f(g8[1]);
          a8[2] += av * b2f(g8[2]); a8[3] += av * b2f(g8[3]);
          a8[4] += av * b2f(g8[4]); a8[5] += av * b2f(g8[5]);
          a8[6] += av * b2f(g8[6]); a8[7] += av * b2f(g8[7]);
        }
        #pragma unroll
        for (int j = 0; j < 8; ++j) RD[(cg*8 + j)*8 + sg] = a8[j];
      }
      __syncthreads();
      {
        int n = ch*256 + tx;
        float sum = 0.f;
        #pragma unroll
        for (int k = 0; k < 8; ++k) sum += RD[tx*8 + k];
        GL[tx] = sum + whh_g[b*2048 + n] + bias_p[n];
      }
      __syncthreads();
      if (tx < 64) {
        int h = ch*64 + tx;
        float iv = GL[tx*4+0], fv = GL[tx*4+1], gv = GL[tx*4+2], ov = GL[tx*4+3];
        float co = c_st[b*512 + h];
        float cn = sigf_(fv)*co + sigf_(iv)*tanhf_(gv);
        float sn = sigf_(ov)*tanhf_(cn);
        c_st[b*512 + h] = cn;
        Abf[((size_t)t*32 + b)*1536 + h] = f2b(sn);
      }
      // ct partial: sum_s alpha[s] * hs[s*32+b][jj], jj = ch*128 + cg2*8 .. +8
      {
        const int cg2 = tx & 15, sg2 = tx >> 4;  // 16 s-groups of 8
        const int jj = ch*128 + cg2*8;
        float c8[8] = {0.f,0.f,0.f,0.f,0.f,0.f,0.f,0.f};
        #pragma unroll
        for (int k = 0; k < 8; ++k) {
          int s = sg2*8 + k;
          float av = AL[s];
          bf16x8 h8 = *(const bf16x8*)&hs_b[((size_t)s*32 + b)*1024 + jj];
          c8[0] += av * b2f(h8[0]); c8[1] += av * b2f(h8[1]);
          c8[2] += av * b2f(h8[2]); c8[3] += av * b2f(h8[3]);
          c8[4] += av * b2f(h8[4]); c8[5] += av * b2f(h8[5]);
          c8[6] += av * b2f(h8[6]); c8[7] += av * b2f(h8[7]);
        }
        __syncthreads();
        #pragma unroll
        for (int j = 0; j < 8; ++j) RD[(cg2*8 + j)*16 + sg2] = c8[j];
      }
      __syncthreads();
      if (tx < 128) {
        float sum = 0.f;
        #pragma unroll
        for (int k = 0; k < 16; ++k) sum += RD[tx*16 + k];
        Abf[((size_t)t*32 + b)*1536 + 512 + ch*128 + tx] = f2b(sum);
      }
    }
    gbar(bar, w, &s_dead);
  }
}

// ---------------- loss + softmax normalize ----------------
__global__ __launch_bounds__(64) void k_loss(const float* __restrict__ L, const float* __restrict__ Z,
                                             const int* __restrict__ t_idx, const float* __restrict__ t_mask,
                                             float* __restrict__ out)
{
  const int b = blockIdx.x, t = threadIdx.x;
  const int row = t*32 + b;
  int id = t_idx[t*32 + b];
  float m = t_mask[t*32 + b];
  float l = L[(size_t)row*32000 + id];
  float v = (__logf(Z[row]) - l) * m;
  float vm = v, mm = m;
  for (int o = 32; o > 0; o >>= 1) { vm += __shfl_down(vm, o, 64); mm += __shfl_down(mm, o, 64); }
  if (t == 0) out[b] = vm / mm;
}

__global__ __launch_bounds__(256) void k_s2(float* __restrict__ L, const float* __restrict__ Z)
{
  const int row = blockIdx.x, tx = threadIdx.x;
  float* p = L + (size_t)row*32000;
  float rz = 1.f / Z[row];
  for (int n = tx; n < 32000; n += 256) p[n] = __expf(p[n]) * rz;
}

// ---------------- host ----------------
extern "C" void kernel_launch(void* const* d_in, const int* in_sizes, int n_in,
                              void* d_out, int out_size, void* d_ws, size_t ws_size,
                              hipStream_t stream)
{
  (void)in_sizes; (void)n_in; (void)out_size;
  const float* h_s    = (const float*)d_in[0];
  const float* s_mask = (const float*)d_in[1];
  const float* w_a    = (const float*)d_in[2];
  const float* v_a    = (const float*)d_in[3];
  const float* u_a    = (const float*)d_in[4];
  const float* w_b    = (const float*)d_in[5];
  const float* v_b    = (const float*)d_in[6];
  const float* W_ih   = (const float*)d_in[7];
  const float* W_hh   = (const float*)d_in[8];
  const float* b_ih   = (const float*)d_in[9];
  const float* b_hh   = (const float*)d_in[10];
  const float* t_mask = (const float*)d_in[11];
  const int*   t_idx  = (const int*)d_in[12];
  float* out = (float*)d_out;
  float* logits = out + 32;

  char* w = (char*)d_ws;
  size_t off = 0;
  auto take = [&](size_t bytes) -> void* {
    void* p = w + off; off += (bytes + 255) & ~(size_t)255; return p;
  };
  unsigned* bar          = (unsigned*)take(2048);
  float* c_st            = (float*)take((size_t)32*512*4);
  float* sva_g           = (float*)take((size_t)32*512*4);
  float* whh_g           = (float*)take((size_t)32*2048*4);
  float* scores_g        = (float*)take((size_t)32*128*4);
  float* Z               = (float*)take((size_t)2048*4);
  float* bias_p          = (float*)take((size_t)2048*4);
  unsigned short* hs_b   = (unsigned short*)take((size_t)4096*1024*2);
  unsigned short* Wcomb  = (unsigned short*)take((size_t)2560*1024*2);
  unsigned short* Wv     = (unsigned short*)take((size_t)512*512*2);
  unsigned short* Whh_p  = (unsigned short*)take((size_t)2048*512*2);
  unsigned short* wa_hb  = (unsigned short*)take((size_t)4096*512*2);
  unsigned short* G      = (unsigned short*)take((size_t)4096*2048*2);
  unsigned short* Abf    = (unsigned short*)take((size_t)2048*1536*2);
  size_t base_need = off;
  bool useBt = (ws_size >= base_need + (size_t)32000*1536*2 + 256);
  unsigned short* Bt = useBt ? (unsigned short*)take((size_t)32000*1536*2) : nullptr;

  hipMemsetAsync(bar, 0, 2048, stream);
  hipMemsetAsync(Z, 0, 2048*4, stream);
  k_convert<<<4096, 256, 0, stream>>>(h_s, w_a, W_ih, v_a, W_hh, b_ih, b_hh,
                                      hs_b, Wcomb, Wv, Whh_p, bias_p);
  if (useBt)
    k_convB<<<dim3(24, 500), 256, 0, stream>>>(w_b, v_b, Bt);
  // [wa_h | G] = h_s @ [w_a | W_ih^T(perm)] : M=4096, N=2560, K=1024
  k_gemm<<<dim3(32,20), 256, 0, stream>>>(hs_b, nullptr, nullptr, 0, Wcomb, 1,
                                          wa_hb, G, 512, 512, 2048, 1, nullptr,
                                          4096, 2560, 1024);
  k_recur<<<NWG_, 256, 0, stream>>>(wa_hb, G, hs_b, Wv, Whh_p, bias_p, s_mask, u_a,
                                    c_st, sva_g, whh_g, scores_g, Abf, bar);
  // logits = [s_new|ct] @ [w_b; v_b] : M=2048, N=32000, K=1536 (+fused Z row-sums)
  if (useBt)
    k_gemm<<<dim3(16,250), 256, 0, stream>>>(Abf, nullptr, nullptr, 0, Bt, 1,
                                             logits, logits, 32000, 32000, 32000, 0, Z,
                                             2048, 32000, 1536);
  else
    k_gemm<<<dim3(16,250), 256, 0, stream>>>(Abf, w_b, v_b, 512, nullptr, 0,
                                             logits, logits, 32000, 32000, 32000, 0, Z,
                                             2048, 32000, 1536);
  k_loss<<<32, 64, 0, stream>>>(logits, Z, t_idx, t_mask, out);
  k_s2<<<2048, 256, 0, stream>>>(logits, Z);
}